// Round 1
// baseline (315.712 us; speedup 1.0000x reference)
//
#include <hip/hip_runtime.h>
#include <hip/hip_bf16.h>

typedef __attribute__((ext_vector_type(8))) short short8;
typedef __attribute__((ext_vector_type(4))) float f32x4;
typedef __attribute__((ext_vector_type(4))) unsigned short u16x4;

#define BM 128
#define BN 128
#define BK 32

__device__ __forceinline__ unsigned short f2bf(float f) {
  union { float f; unsigned u; } v; v.f = f;
  unsigned r = v.u + 0x7fffu + ((v.u >> 16) & 1u);
  return (unsigned short)(r >> 16);
}

// Stage a [128 rows x 32 cols] bf16 tile from row-major src (leading dim ld)
// into linear LDS [128][32] via async global_load_lds, 16B per lane.
// LDS dest base must be wave-uniform; lane l lands at base + 16*l (linear). 
__device__ __forceinline__ void stage_tile(const unsigned short* src, int ld, int k0,
                                           unsigned short* lds, int t) {
  const int w = t >> 6;           // wave id (uniform)
  const int coff = (t & 3) * 8;   // element col offset
#pragma unroll
  for (int i = 0; i < 2; ++i) {
    int r = i * 64 + (t >> 2);
    const unsigned short* g = src + (size_t)r * ld + k0 + coff;
    unsigned short* l = lds + i * 2048 + w * 512;  // (i*64 + w*16) rows * 32 elems
    __builtin_amdgcn_global_load_lds((const __attribute__((address_space(1))) void*)g,
                                     (__attribute__((address_space(3))) void*)l,
                                     16, 0, 0);
  }
}

// EPI=0: C = A*Bt^T epilogue -> W bf16 + row-sum atomics into denom
// EPI=1: C = A*Bt^T epilogue -> out fp32 scaled by 1/(denom+1e-8)
template <int EPI>
__global__ __launch_bounds__(256) void rbf_gemm(
    const unsigned short* __restrict__ A, const unsigned short* __restrict__ Bt,
    int Ncols, int K,
    const float* __restrict__ xsq, const float* __restrict__ psq,
    const float* __restrict__ rtemp, unsigned short* __restrict__ Wout,
    float* __restrict__ denom, const float* __restrict__ denin,
    float* __restrict__ outp, int row0, int ldOut) {
  __shared__ __align__(16) unsigned short sA[BM * BK];
  __shared__ __align__(16) unsigned short sB[BN * BK];
  const int t = threadIdx.x;
  const int lane = t & 63;
  const int wid = t >> 6;
  const int wr = wid >> 1, wc = wid & 1;   // 2x2 waves, each owns 64x64
  const int lr = lane & 15, lg = lane >> 4;

  const int nb = Ncols / BN;
  const int nwg = gridDim.x;
  int swz = blockIdx.x;
  if ((nwg & 7) == 0) {  // bijective XCD swizzle
    int cpx = nwg >> 3;
    swz = (swz & 7) * cpx + (swz >> 3);
  }
  const int bm = swz / nb, bn = swz % nb;

  const unsigned short* Ab = A + (size_t)bm * BM * K;
  const unsigned short* Bb = Bt + (size_t)bn * BN * K;

  f32x4 acc[4][4];
#pragma unroll
  for (int i = 0; i < 4; ++i)
#pragma unroll
    for (int j = 0; j < 4; ++j) acc[i][j] = (f32x4){0.f, 0.f, 0.f, 0.f};

  for (int k0 = 0; k0 < K; k0 += BK) {
    stage_tile(Ab, K, k0, sA, t);
    stage_tile(Bb, K, k0, sB, t);
    __syncthreads();
    short8 af[4], bf[4];
#pragma unroll
    for (int mi = 0; mi < 4; ++mi)
      af[mi] = *(const short8*)&sA[(wr * 64 + mi * 16 + lr) * BK + lg * 8];
#pragma unroll
    for (int ni = 0; ni < 4; ++ni)
      bf[ni] = *(const short8*)&sB[(wc * 64 + ni * 16 + lr) * BK + lg * 8];
#pragma unroll
    for (int mi = 0; mi < 4; ++mi)
#pragma unroll
      for (int ni = 0; ni < 4; ++ni)
        acc[mi][ni] = __builtin_amdgcn_mfma_f32_16x16x32_bf16(af[mi], bf[ni], acc[mi][ni], 0, 0, 0);
    __syncthreads();
  }

  if (EPI == 0) {
    // cross -> dist -> weight; store bf16 W; row-sum partials -> denom
    float rs[4][4];
#pragma unroll
    for (int mi = 0; mi < 4; ++mi)
#pragma unroll
      for (int j = 0; j < 4; ++j) rs[mi][j] = 0.f;

#pragma unroll
    for (int ni = 0; ni < 4; ++ni) {
      const int col = bn * BN + wc * 64 + ni * 16 + lr;
      const float ps = psq[col];
      const float rt = rtemp[col];
#pragma unroll
      for (int mi = 0; mi < 4; ++mi) {
#pragma unroll
        for (int j = 0; j < 4; ++j) {
          const int lrow = bm * BM + wr * 64 + mi * 16 + lg * 4 + j;
          const int grow = row0 + lrow;
          const float cross = acc[mi][ni][j];
          float d2 = xsq[grow] + ps - 2.0f * cross;
          float dist = sqrtf(fmaxf(d2, 0.0f));
          float wgt = __expf(-dist * rt);
          Wout[(size_t)lrow * ldOut + col] = f2bf(wgt);
          rs[mi][j] += wgt;
        }
      }
    }
#pragma unroll
    for (int mi = 0; mi < 4; ++mi)
#pragma unroll
      for (int j = 0; j < 4; ++j) {
        float v = rs[mi][j];
        v += __shfl_xor(v, 1);
        v += __shfl_xor(v, 2);
        v += __shfl_xor(v, 4);
        v += __shfl_xor(v, 8);
        if (lr == 0) {
          const int grow = row0 + bm * BM + wr * 64 + mi * 16 + lg * 4 + j;
          atomicAdd(&denom[grow], v);
        }
      }
  } else {
    // scale by 1/(denom + 1e-8), write fp32 out
#pragma unroll
    for (int mi = 0; mi < 4; ++mi) {
#pragma unroll
      for (int j = 0; j < 4; ++j) {
        const int lrow = bm * BM + wr * 64 + mi * 16 + lg * 4 + j;
        const int grow = row0 + lrow;
        const float rd = 1.0f / (denin[grow] + 1e-8f);
#pragma unroll
        for (int ni = 0; ni < 4; ++ni) {
          const int col = bn * BN + wc * 64 + ni * 16 + lr;
          outp[(size_t)grow * ldOut + col] = acc[mi][ni][j] * rd;
        }
      }
    }
  }
}

// One block per row: cast fp32 row -> bf16, compute sum of squares.
__global__ void prep_rows(const float* __restrict__ in, unsigned short* __restrict__ outb,
                          float* __restrict__ sq, int D) {
  const int row = blockIdx.x;
  const int t = threadIdx.x;
  const float4 v = ((const float4*)(in + (size_t)row * D))[t];
  u16x4 o = {f2bf(v.x), f2bf(v.y), f2bf(v.z), f2bf(v.w)};
  *(u16x4*)(outb + (size_t)row * D + t * 4) = o;
  float s = v.x * v.x + v.y * v.y + v.z * v.z + v.w * v.w;
  for (int off = 32; off; off >>= 1) s += __shfl_xor(s, off);
  __shared__ float ws[16];
  if ((t & 63) == 0) ws[t >> 6] = s;
  __syncthreads();
  if (t == 0) {
    float tot = 0.f;
    const int nw = blockDim.x >> 6;
    for (int i = 0; i < nw; ++i) tot += ws[i];
    sq[row] = tot;
  }
}

__global__ void prep_scale(const float* __restrict__ tmp, const float* __restrict__ sc,
                           float* __restrict__ rtemp, int N) {
  const int i = blockIdx.x * blockDim.x + threadIdx.x;
  if (i < N) rtemp[i] = 1.0f / ((fabsf(tmp[i]) + 0.1f) * sc[i]);
}

// Transpose values [N][D] fp32 -> vT [D][N] bf16
__global__ void prep_vT(const float* __restrict__ vals, unsigned short* __restrict__ vT,
                        int N, int D) {
  __shared__ float tile[32][33];
  const int nt = blockIdx.x, dt = blockIdx.y;
  const int tx = threadIdx.x, ty = threadIdx.y;  // (32, 8)
#pragma unroll
  for (int i = 0; i < 4; ++i) {
    int r = nt * 32 + ty + i * 8;
    tile[ty + i * 8][tx] = vals[(size_t)r * D + dt * 32 + tx];
  }
  __syncthreads();
#pragma unroll
  for (int i = 0; i < 4; ++i) {
    int d = dt * 32 + ty + i * 8;
    vT[(size_t)d * N + nt * 32 + tx] = f2bf(tile[tx][ty + i * 8]);
  }
}

extern "C" void kernel_launch(void* const* d_in, const int* in_sizes, int n_in,
                              void* d_out, int out_size, void* d_ws, size_t ws_size,
                              hipStream_t stream) {
  const float* x = (const float*)d_in[0];
  const float* pos = (const float*)d_in[1];
  const float* vals = (const float*)d_in[2];
  const float* temp = (const float*)d_in[3];
  const float* nsc = (const float*)d_in[4];
  float* out = (float*)d_out;

  const int N = in_sizes[3];          // 4096
  const int D = in_sizes[1] / N;      // 512
  const int M = in_sizes[0] / D;      // 16384

  char* ws = (char*)d_ws;
  size_t off = 0;
  auto alloc = [&](size_t bytes) {
    void* p = ws + off;
    off = (off + bytes + 255) & ~(size_t)255;
    return p;
  };
  unsigned short* xb = (unsigned short*)alloc((size_t)M * D * 2);
  unsigned short* pb = (unsigned short*)alloc((size_t)N * D * 2);
  unsigned short* vT = (unsigned short*)alloc((size_t)D * N * 2);
  float* xsq = (float*)alloc((size_t)M * 4);
  float* psq = (float*)alloc((size_t)N * 4);
  float* rtemp = (float*)alloc((size_t)N * 4);
  float* denom = (float*)alloc((size_t)M * 4);

  size_t avail = ws_size > off ? ws_size - off : 0;
  long long mc_ll = (long long)(avail / ((size_t)N * 2));
  int Mc = (int)((mc_ll / BM) * BM);
  if (Mc > M) Mc = M;
  if (Mc < BM) Mc = BM;  // minimal fallback
  unsigned short* W = (unsigned short*)alloc((size_t)Mc * N * 2);

  hipMemsetAsync(denom, 0, (size_t)M * 4, stream);
  prep_rows<<<M, D / 4, 0, stream>>>(x, xb, xsq, D);
  prep_rows<<<N, D / 4, 0, stream>>>(pos, pb, psq, D);
  prep_scale<<<(N + 255) / 256, 256, 0, stream>>>(temp, nsc, rtemp, N);
  dim3 tg(N / 32, D / 32);
  prep_vT<<<tg, dim3(32, 8), 0, stream>>>(vals, vT, N, D);

  for (int row0 = 0; row0 < M; row0 += Mc) {
    const int mc = (M - row0) < Mc ? (M - row0) : Mc;
    const int g1 = (mc / BM) * (N / BN);
    rbf_gemm<0><<<g1, 256, 0, stream>>>(xb + (size_t)row0 * D, pb, N, D,
                                        xsq, psq, rtemp, W, denom, nullptr,
                                        nullptr, row0, N);
    const int g2 = (mc / BM) * (D / BN);
    rbf_gemm<1><<<g2, 256, 0, stream>>>(W, vT, D, N,
                                        nullptr, nullptr, nullptr, nullptr,
                                        nullptr, denom, out, row0, D);
  }
}

// Round 2
// 286.811 us; speedup vs baseline: 1.1008x; 1.1008x over previous
//
#include <hip/hip_runtime.h>
#include <hip/hip_bf16.h>

typedef __attribute__((ext_vector_type(8))) short short8;
typedef __attribute__((ext_vector_type(4))) float f32x4;
typedef __attribute__((ext_vector_type(4))) unsigned short u16x4;

__device__ __forceinline__ unsigned short f2bf(float f) {
  union { float f; unsigned u; } v; v.f = f;
  unsigned r = v.u + 0x7fffu + ((v.u >> 16) & 1u);
  return (unsigned short)(r >> 16);
}

// Stage an [R rows x 64 cols] bf16 tile from row-major src (ld elems) into
// LDS (linear [R][64]) via global_load_lds 16B/lane. The 16B chunk index is
// XOR-swizzled (c ^ (row&7)) on the GLOBAL source side; LDS dest stays
// linear (gload_lds requires base + lane*16). Readers apply the same XOR.
template <int R>
__device__ __forceinline__ void stage64(const unsigned short* src, int ld, int k0,
                                        unsigned short* lds, int t) {
#pragma unroll
  for (int i = 0; i < R / 32; ++i) {
    const int idx = i * 256 + t;
    const int r = idx >> 3;          // 8 lanes per 128B row
    const int c = idx & 7;           // 16B chunk within row
    const int cs = c ^ (r & 7);      // swizzled source chunk
    const unsigned short* g = src + (size_t)r * ld + k0 + cs * 8;
    // wave-uniform LDS base (elems); lane lands at base + lane*16B
    unsigned short* l = lds + ((size_t)(i * 256 + (t >> 6) * 64)) * 8;
    __builtin_amdgcn_global_load_lds((const __attribute__((address_space(1))) void*)g,
                                     (__attribute__((address_space(3))) void*)l,
                                     16, 0, 0);
  }
}

// C = A * Bt^T, tiles BM x 128, BK=64, 256 threads as 2x2 waves (each 32*TM/2 x 64).
// EPI=0 (TM=4, BM=128): epilogue -> W bf16 (via LDS bounce, coalesced) + row-sum atomics
// EPI=1 (TM=2, BM=64):  epilogue -> out fp32 scaled by 1/(denom+1e-8)
template <int EPI, int TM>
__global__ __launch_bounds__(256) void rbf_gemm(
    const unsigned short* __restrict__ A, const unsigned short* __restrict__ Bt,
    int Ncols, int K,
    const float* __restrict__ xsq, const float* __restrict__ psq,
    const float* __restrict__ rtemp, unsigned short* __restrict__ Wout,
    float* __restrict__ denom, const float* __restrict__ denin,
    float* __restrict__ outp, int row0, int ldOut) {
  constexpr int BM = TM * 32;
  __shared__ __align__(16) unsigned short smem[16384];  // 32 KB
  unsigned short* sA = smem;
  unsigned short* sB = smem + BM * 64;

  const int t = threadIdx.x;
  const int lane = t & 63;
  const int wid = t >> 6;
  const int wr = wid >> 1, wc = wid & 1;  // 2x2 waves
  const int lr = lane & 15, lg = lane >> 4;

  const int nb = Ncols / 128;
  const int nwg = gridDim.x;
  int swz = blockIdx.x;
  if ((nwg & 7) == 0) {  // bijective XCD swizzle
    int cpx = nwg >> 3;
    swz = (swz & 7) * cpx + (swz >> 3);
  }
  const int bm = swz / nb, bn = swz % nb;

  const unsigned short* Ab = A + (size_t)bm * BM * K;
  const unsigned short* Bb = Bt + (size_t)bn * 128 * K;

  f32x4 acc[TM][4];
#pragma unroll
  for (int i = 0; i < TM; ++i)
#pragma unroll
    for (int j = 0; j < 4; ++j) acc[i][j] = (f32x4){0.f, 0.f, 0.f, 0.f};

  for (int k0 = 0; k0 < K; k0 += 64) {
    stage64<BM>(Ab, K, k0, sA, t);
    stage64<128>(Bb, K, k0, sB, t);
    __syncthreads();
    short8 af[TM][2], bf[4][2];
#pragma unroll
    for (int mi = 0; mi < TM; ++mi) {
      const int ar = wr * (TM * 16) + mi * 16 + lr;
#pragma unroll
      for (int ks = 0; ks < 2; ++ks)
        af[mi][ks] = *(const short8*)&sA[ar * 64 + (((ks << 2) | lg) ^ (ar & 7)) * 8];
    }
#pragma unroll
    for (int ni = 0; ni < 4; ++ni) {
      const int br = wc * 64 + ni * 16 + lr;
#pragma unroll
      for (int ks = 0; ks < 2; ++ks)
        bf[ni][ks] = *(const short8*)&sB[br * 64 + (((ks << 2) | lg) ^ (br & 7)) * 8];
    }
#pragma unroll
    for (int ks = 0; ks < 2; ++ks)
#pragma unroll
      for (int mi = 0; mi < TM; ++mi)
#pragma unroll
        for (int ni = 0; ni < 4; ++ni)
          acc[mi][ni] = __builtin_amdgcn_mfma_f32_16x16x32_bf16(af[mi][ks], bf[ni][ks],
                                                                acc[mi][ni], 0, 0, 0);
    __syncthreads();
  }

  if (EPI == 0) {
    // cross -> dist -> weight; W tile -> LDS (swizzled) then coalesced copy-out;
    // row-sum partials -> denom atomics.
    float rs[TM][4];
#pragma unroll
    for (int mi = 0; mi < TM; ++mi)
#pragma unroll
      for (int j = 0; j < 4; ++j) rs[mi][j] = 0.f;

#pragma unroll
    for (int ni = 0; ni < 4; ++ni) {
      const int lcol = wc * 64 + ni * 16 + lr;
      const int col = bn * 128 + lcol;
      const float ps = psq[col];
      const float rt = rtemp[col];
#pragma unroll
      for (int mi = 0; mi < TM; ++mi) {
#pragma unroll
        for (int j = 0; j < 4; ++j) {
          const int lrow = wr * 64 + mi * 16 + lg * 4 + j;
          const int grow = row0 + bm * BM + lrow;
          const float cross = acc[mi][ni][j];
          float d2 = xsq[grow] + ps - 2.0f * cross;
          float dist = sqrtf(fmaxf(d2, 0.0f));
          float wgt = __expf(-dist * rt);
          // swizzled W-tile store: 16B chunk h XORed with row&15
          const int h = lcol >> 3;
          smem[lrow * 128 + ((h ^ (lrow & 15)) << 3) + (lcol & 7)] = f2bf(wgt);
          rs[mi][j] += wgt;
        }
      }
    }
    __syncthreads();
    // coalesced copy-out: 2048 16B-chunks, 8 rounds of 256 lanes
#pragma unroll
    for (int i = 0; i < 8; ++i) {
      const int id = i * 256 + t;
      const int r = id >> 4, h = id & 15;
      short8 v = *(const short8*)&smem[r * 128 + ((h ^ (r & 15)) << 3)];
      *(short8*)&Wout[(size_t)(bm * BM + r) * ldOut + bn * 128 + h * 8] = v;
    }
#pragma unroll
    for (int mi = 0; mi < TM; ++mi)
#pragma unroll
      for (int j = 0; j < 4; ++j) {
        float v = rs[mi][j];
        v += __shfl_xor(v, 1);
        v += __shfl_xor(v, 2);
        v += __shfl_xor(v, 4);
        v += __shfl_xor(v, 8);
        if (lr == 0) {
          const int grow = row0 + bm * BM + wr * 64 + mi * 16 + lg * 4 + j;
          atomicAdd(&denom[grow], v);
        }
      }
  } else {
    // scale by 1/(denom + 1e-8), write fp32 out
#pragma unroll
    for (int mi = 0; mi < TM; ++mi) {
#pragma unroll
      for (int j = 0; j < 4; ++j) {
        const int lrow = bm * BM + wr * (TM * 16) + mi * 16 + lg * 4 + j;
        const int grow = row0 + lrow;
        const float rd = 1.0f / (denin[grow] + 1e-8f);
#pragma unroll
        for (int ni = 0; ni < 4; ++ni) {
          const int col = bn * 128 + wc * 64 + ni * 16 + lr;
          outp[(size_t)grow * ldOut + col] = acc[mi][ni][j] * rd;
        }
      }
    }
  }
}

// One block per row: cast fp32 row -> bf16, compute sum of squares.
__global__ void prep_rows(const float* __restrict__ in, unsigned short* __restrict__ outb,
                          float* __restrict__ sq, int D) {
  const int row = blockIdx.x;
  const int t = threadIdx.x;
  const float4 v = ((const float4*)(in + (size_t)row * D))[t];
  u16x4 o = {f2bf(v.x), f2bf(v.y), f2bf(v.z), f2bf(v.w)};
  *(u16x4*)(outb + (size_t)row * D + t * 4) = o;
  float s = v.x * v.x + v.y * v.y + v.z * v.z + v.w * v.w;
  for (int off = 32; off; off >>= 1) s += __shfl_xor(s, off);
  __shared__ float ws[16];
  if ((t & 63) == 0) ws[t >> 6] = s;
  __syncthreads();
  if (t == 0) {
    float tot = 0.f;
    const int nw = blockDim.x >> 6;
    for (int i = 0; i < nw; ++i) tot += ws[i];
    sq[row] = tot;
  }
}

__global__ void prep_scale(const float* __restrict__ tmp, const float* __restrict__ sc,
                           float* __restrict__ rtemp, int N) {
  const int i = blockIdx.x * blockDim.x + threadIdx.x;
  if (i < N) rtemp[i] = 1.0f / ((fabsf(tmp[i]) + 0.1f) * sc[i]);
}

// Transpose values [N][D] fp32 -> vT [D][N] bf16
__global__ void prep_vT(const float* __restrict__ vals, unsigned short* __restrict__ vT,
                        int N, int D) {
  __shared__ float tile[32][33];
  const int nt = blockIdx.x, dt = blockIdx.y;
  const int tx = threadIdx.x, ty = threadIdx.y;  // (32, 8)
#pragma unroll
  for (int i = 0; i < 4; ++i) {
    int r = nt * 32 + ty + i * 8;
    tile[ty + i * 8][tx] = vals[(size_t)r * D + dt * 32 + tx];
  }
  __syncthreads();
#pragma unroll
  for (int i = 0; i < 4; ++i) {
    int d = dt * 32 + ty + i * 8;
    vT[(size_t)d * N + nt * 32 + tx] = f2bf(tile[tx][ty + i * 8]);
  }
}

extern "C" void kernel_launch(void* const* d_in, const int* in_sizes, int n_in,
                              void* d_out, int out_size, void* d_ws, size_t ws_size,
                              hipStream_t stream) {
  const float* x = (const float*)d_in[0];
  const float* pos = (const float*)d_in[1];
  const float* vals = (const float*)d_in[2];
  const float* temp = (const float*)d_in[3];
  const float* nsc = (const float*)d_in[4];
  float* out = (float*)d_out;

  const int N = in_sizes[3];          // 4096
  const int D = in_sizes[1] / N;      // 512
  const int M = in_sizes[0] / D;      // 16384

  char* ws = (char*)d_ws;
  size_t off = 0;
  auto alloc = [&](size_t bytes) {
    void* p = ws + off;
    off = (off + bytes + 255) & ~(size_t)255;
    return p;
  };
  unsigned short* xb = (unsigned short*)alloc((size_t)M * D * 2);
  unsigned short* pb = (unsigned short*)alloc((size_t)N * D * 2);
  unsigned short* vT = (unsigned short*)alloc((size_t)D * N * 2);
  float* xsq = (float*)alloc((size_t)M * 4);
  float* psq = (float*)alloc((size_t)N * 4);
  float* rtemp = (float*)alloc((size_t)N * 4);
  float* denom = (float*)alloc((size_t)M * 4);

  size_t avail = ws_size > off ? ws_size - off : 0;
  long long mc_ll = (long long)(avail / ((size_t)N * 2));
  int Mc = (int)((mc_ll / 128) * 128);
  if (Mc > M) Mc = M;
  if (Mc < 128) Mc = 128;  // minimal fallback
  unsigned short* W = (unsigned short*)alloc((size_t)Mc * N * 2);

  hipMemsetAsync(denom, 0, (size_t)M * 4, stream);
  prep_rows<<<M, D / 4, 0, stream>>>(x, xb, xsq, D);
  prep_rows<<<N, D / 4, 0, stream>>>(pos, pb, psq, D);
  prep_scale<<<(N + 255) / 256, 256, 0, stream>>>(temp, nsc, rtemp, N);
  dim3 tg(N / 32, D / 32);
  prep_vT<<<tg, dim3(32, 8), 0, stream>>>(vals, vT, N, D);

  for (int row0 = 0; row0 < M; row0 += Mc) {
    const int mc = (M - row0) < Mc ? (M - row0) : Mc;
    const int g1 = (mc / 128) * (N / 128);
    rbf_gemm<0, 4><<<g1, 256, 0, stream>>>(xb + (size_t)row0 * D, pb, N, D,
                                           xsq, psq, rtemp, W, denom, nullptr,
                                           nullptr, row0, N);
    const int g2 = (mc / 64) * (D / 128);
    rbf_gemm<1, 2><<<g2, 256, 0, stream>>>(W, vT, D, N,
                                           nullptr, nullptr, nullptr, nullptr,
                                           nullptr, denom, out, row0, D);
  }
}

// Round 3
// 282.812 us; speedup vs baseline: 1.1163x; 1.0141x over previous
//
#include <hip/hip_runtime.h>
#include <hip/hip_bf16.h>

typedef __attribute__((ext_vector_type(8))) short short8;
typedef __attribute__((ext_vector_type(4))) float f32x4;
typedef __attribute__((ext_vector_type(4))) unsigned short u16x4;

__device__ __forceinline__ unsigned short f2bf(float f) {
  union { float f; unsigned u; } v; v.f = f;
  unsigned r = v.u + 0x7fffu + ((v.u >> 16) & 1u);
  return (unsigned short)(r >> 16);
}

// Stage an [R rows x 32 cols] bf16 tile from row-major src (ld elems) into
// LDS (linear [R][32]) via global_load_lds 16B/lane. 16B chunk index (0..3)
// XOR-swizzled with (row&3) on the GLOBAL source side; LDS dest stays linear.
// Readers apply the same XOR.
template <int R>
__device__ __forceinline__ void stage32(const unsigned short* src, int ld, int k0,
                                        unsigned short* lds, int t) {
#pragma unroll
  for (int i = 0; i < R / 64; ++i) {
    const int idx = i * 256 + t;
    const int r = idx >> 2;          // 4 lanes per 64B row
    const int c = idx & 3;           // 16B chunk within row
    const int cs = c ^ (r & 3);      // swizzled source chunk
    const unsigned short* g = src + (size_t)r * ld + k0 + cs * 8;
    unsigned short* l = lds + (size_t)(i * 2048 + (t >> 6) * 512);
    __builtin_amdgcn_global_load_lds((const __attribute__((address_space(1))) void*)g,
                                     (__attribute__((address_space(3))) void*)l,
                                     16, 0, 0);
  }
}

// C = A * Bt^T, tile BM x 128, BK=32, double-buffered prefetch pipeline.
// 256 threads as 2x2 waves.
// EPI=0 (TM=4, BM=128): epilogue -> W bf16 (LDS bounce, coalesced) + row-sum
//                        partials (no atomics) into part[(bn*2+wc)][row]
// EPI=1 (TM=2, BM=64):  epilogue -> out fp32 scaled by 1/(denom+1e-8)
template <int EPI, int TM>
__global__ __launch_bounds__(256) void rbf_gemm(
    const unsigned short* __restrict__ A, const unsigned short* __restrict__ Bt,
    int Ncols, int K,
    const float* __restrict__ xsq, const float* __restrict__ psq,
    const float* __restrict__ rtemp, unsigned short* __restrict__ Wout,
    float* __restrict__ part, int Mtot, const float* __restrict__ denin,
    float* __restrict__ outp, int row0, int ldOut) {
  constexpr int BM = TM * 32;
  constexpr int HALF = (BM + 128) * 32;  // elems per dbuf half
  __shared__ __align__(16) unsigned short smem[2 * HALF];

  const int t = threadIdx.x;
  const int lane = t & 63;
  const int wid = t >> 6;
  const int wr = wid >> 1, wc = wid & 1;  // 2x2 waves
  const int lr = lane & 15, lg = lane >> 4;

  const int nb = Ncols / 128;
  const int nwg = gridDim.x;
  int swz = blockIdx.x;
  if ((nwg & 7) == 0) {  // bijective XCD swizzle
    int cpx = nwg >> 3;
    swz = (swz & 7) * cpx + (swz >> 3);
  }
  const int bm = swz / nb, bn = swz % nb;

  const unsigned short* Ab = A + (size_t)bm * BM * K;
  const unsigned short* Bb = Bt + (size_t)bn * 128 * K;

  f32x4 acc[TM][4];
#pragma unroll
  for (int i = 0; i < TM; ++i)
#pragma unroll
    for (int j = 0; j < 4; ++j) acc[i][j] = (f32x4){0.f, 0.f, 0.f, 0.f};

  // prologue: stage tile 0 into buffer 0
  stage32<BM>(Ab, K, 0, smem, t);
  stage32<128>(Bb, K, 0, smem + BM * 32, t);
  __syncthreads();

  int cur = 0;
  for (int k0 = 0; k0 < K; k0 += 32) {
    const int nxt = cur ^ 1;
    if (k0 + 32 < K) {  // issue next-tile loads BEFORE compute (overlap)
      stage32<BM>(Ab, K, k0 + 32, smem + nxt * HALF, t);
      stage32<128>(Bb, K, k0 + 32, smem + nxt * HALF + BM * 32, t);
    }
    const unsigned short* sA = smem + cur * HALF;
    const unsigned short* sB = sA + BM * 32;
    short8 af[TM], bf[4];
#pragma unroll
    for (int mi = 0; mi < TM; ++mi) {
      const int ar = wr * (TM * 16) + mi * 16 + lr;
      af[mi] = *(const short8*)&sA[ar * 32 + ((lg ^ (ar & 3)) << 3)];
    }
#pragma unroll
    for (int ni = 0; ni < 4; ++ni) {
      const int br = wc * 64 + ni * 16 + lr;
      bf[ni] = *(const short8*)&sB[br * 32 + ((lg ^ (br & 3)) << 3)];
    }
#pragma unroll
    for (int mi = 0; mi < TM; ++mi)
#pragma unroll
      for (int ni = 0; ni < 4; ++ni)
        acc[mi][ni] = __builtin_amdgcn_mfma_f32_16x16x32_bf16(af[mi], bf[ni],
                                                              acc[mi][ni], 0, 0, 0);
    __syncthreads();  // drains vmcnt(0): next tile landed; all waves done with cur
    cur = nxt;
  }

  if (EPI == 0) {
    float rs[TM][4];
#pragma unroll
    for (int mi = 0; mi < TM; ++mi)
#pragma unroll
      for (int j = 0; j < 4; ++j) rs[mi][j] = 0.f;

#pragma unroll
    for (int ni = 0; ni < 4; ++ni) {
      const int lcol = wc * 64 + ni * 16 + lr;
      const int col = bn * 128 + lcol;
      const float ps = psq[col];
      const float rt = rtemp[col];
#pragma unroll
      for (int mi = 0; mi < TM; ++mi) {
#pragma unroll
        for (int j = 0; j < 4; ++j) {
          const int lrow = wr * 64 + mi * 16 + lg * 4 + j;
          const int grow = row0 + bm * BM + lrow;
          const float cross = acc[mi][ni][j];
          float d2 = xsq[grow] + ps - 2.0f * cross;
          float dist = sqrtf(fmaxf(d2, 0.0f));
          float wgt = __expf(-dist * rt);
          const int h = lcol >> 3;
          smem[lrow * 128 + ((h ^ (lrow & 15)) << 3) + (lcol & 7)] = f2bf(wgt);
          rs[mi][j] += wgt;
        }
      }
    }
    __syncthreads();
#pragma unroll
    for (int i = 0; i < 8; ++i) {
      const int id = i * 256 + t;
      const int r = id >> 4, h = id & 15;
      short8 v = *(const short8*)&smem[r * 128 + ((h ^ (r & 15)) << 3)];
      *(short8*)&Wout[(size_t)(bm * BM + r) * ldOut + bn * 128 + h * 8] = v;
    }
    // row-sum partials: unique writer per (bn,wc,row) -> no atomics
    float* slice = part + (size_t)((bn << 1) | wc) * Mtot;
#pragma unroll
    for (int mi = 0; mi < TM; ++mi)
#pragma unroll
      for (int j = 0; j < 4; ++j) {
        float v = rs[mi][j];
        v += __shfl_xor(v, 1);
        v += __shfl_xor(v, 2);
        v += __shfl_xor(v, 4);
        v += __shfl_xor(v, 8);
        if (lr == 0) {
          const int grow = row0 + bm * BM + wr * 64 + mi * 16 + lg * 4 + j;
          slice[grow] = v;
        }
      }
  } else {
#pragma unroll
    for (int mi = 0; mi < TM; ++mi) {
#pragma unroll
      for (int j = 0; j < 4; ++j) {
        const int lrow = bm * BM + wr * (TM * 16) + mi * 16 + lg * 4 + j;
        const int grow = row0 + lrow;
        const float rd = 1.0f / (denin[grow] + 1e-8f);
#pragma unroll
        for (int ni = 0; ni < 4; ++ni) {
          const int col = bn * 128 + wc * 64 + ni * 16 + lr;
          outp[(size_t)grow * ldOut + col] = acc[mi][ni][j] * rd;
        }
      }
    }
  }
}

// denom[m] = sum_s part[s][m]
__global__ void reduce_denom(const float* __restrict__ part, float* __restrict__ denom,
                             int Mtot, int row0, int S) {
  const int m = row0 + blockIdx.x * 128 + threadIdx.x;
  float s = 0.f;
  for (int i = 0; i < S; ++i) s += part[(size_t)i * Mtot + m];
  denom[m] = s;
}

// One block per row: cast fp32 row -> bf16, compute sum of squares.
__global__ void prep_rows(const float* __restrict__ in, unsigned short* __restrict__ outb,
                          float* __restrict__ sq, int D) {
  const int row = blockIdx.x;
  const int t = threadIdx.x;
  const float4 v = ((const float4*)(in + (size_t)row * D))[t];
  u16x4 o = {f2bf(v.x), f2bf(v.y), f2bf(v.z), f2bf(v.w)};
  *(u16x4*)(outb + (size_t)row * D + t * 4) = o;
  float s = v.x * v.x + v.y * v.y + v.z * v.z + v.w * v.w;
  for (int off = 32; off; off >>= 1) s += __shfl_xor(s, off);
  __shared__ float ws[16];
  if ((t & 63) == 0) ws[t >> 6] = s;
  __syncthreads();
  if (t == 0) {
    float tot = 0.f;
    const int nw = blockDim.x >> 6;
    for (int i = 0; i < nw; ++i) tot += ws[i];
    sq[row] = tot;
  }
}

__global__ void prep_scale(const float* __restrict__ tmp, const float* __restrict__ sc,
                           float* __restrict__ rtemp, int N) {
  const int i = blockIdx.x * blockDim.x + threadIdx.x;
  if (i < N) rtemp[i] = 1.0f / ((fabsf(tmp[i]) + 0.1f) * sc[i]);
}

// Transpose values [N][D] fp32 -> vT [D][N] bf16
__global__ void prep_vT(const float* __restrict__ vals, unsigned short* __restrict__ vT,
                        int N, int D) {
  __shared__ float tile[32][33];
  const int nt = blockIdx.x, dt = blockIdx.y;
  const int tx = threadIdx.x, ty = threadIdx.y;  // (32, 8)
#pragma unroll
  for (int i = 0; i < 4; ++i) {
    int r = nt * 32 + ty + i * 8;
    tile[ty + i * 8][tx] = vals[(size_t)r * D + dt * 32 + tx];
  }
  __syncthreads();
#pragma unroll
  for (int i = 0; i < 4; ++i) {
    int d = dt * 32 + ty + i * 8;
    vT[(size_t)d * N + nt * 32 + tx] = f2bf(tile[tx][ty + i * 8]);
  }
}

extern "C" void kernel_launch(void* const* d_in, const int* in_sizes, int n_in,
                              void* d_out, int out_size, void* d_ws, size_t ws_size,
                              hipStream_t stream) {
  const float* x = (const float*)d_in[0];
  const float* pos = (const float*)d_in[1];
  const float* vals = (const float*)d_in[2];
  const float* temp = (const float*)d_in[3];
  const float* nsc = (const float*)d_in[4];
  float* out = (float*)d_out;

  const int N = in_sizes[3];          // 4096
  const int D = in_sizes[1] / N;      // 512
  const int M = in_sizes[0] / D;      // 16384
  const int S = 2 * (N / 128);        // partial slices (64)

  char* ws = (char*)d_ws;
  size_t off = 0;
  auto alloc = [&](size_t bytes) {
    void* p = ws + off;
    off = (off + bytes + 255) & ~(size_t)255;
    return p;
  };
  unsigned short* xb = (unsigned short*)alloc((size_t)M * D * 2);
  unsigned short* pb = (unsigned short*)alloc((size_t)N * D * 2);
  unsigned short* vT = (unsigned short*)alloc((size_t)D * N * 2);
  float* xsq = (float*)alloc((size_t)M * 4);
  float* psq = (float*)alloc((size_t)N * 4);
  float* rtemp = (float*)alloc((size_t)N * 4);
  float* denom = (float*)alloc((size_t)M * 4);
  float* part = (float*)alloc((size_t)S * M * 4);

  size_t avail = ws_size > off ? ws_size - off : 0;
  long long mc_ll = (long long)(avail / ((size_t)N * 2));
  int Mc = (int)((mc_ll / 128) * 128);
  if (Mc > M) Mc = M;
  if (Mc < 128) Mc = 128;  // minimal fallback
  unsigned short* W = (unsigned short*)alloc((size_t)Mc * N * 2);

  prep_rows<<<M, D / 4, 0, stream>>>(x, xb, xsq, D);
  prep_rows<<<N, D / 4, 0, stream>>>(pos, pb, psq, D);
  prep_scale<<<(N + 255) / 256, 256, 0, stream>>>(temp, nsc, rtemp, N);
  dim3 tg(N / 32, D / 32);
  prep_vT<<<tg, dim3(32, 8), 0, stream>>>(vals, vT, N, D);

  for (int row0 = 0; row0 < M; row0 += Mc) {
    const int mc = (M - row0) < Mc ? (M - row0) : Mc;
    const int g1 = (mc / 128) * (N / 128);
    rbf_gemm<0, 4><<<g1, 256, 0, stream>>>(xb + (size_t)row0 * D, pb, N, D,
                                           xsq, psq, rtemp, W, part, M,
                                           nullptr, nullptr, row0, N);
    reduce_denom<<<mc / 128, 128, 0, stream>>>(part, denom, M, row0, S);
    const int g2 = (mc / 64) * (D / 128);
    rbf_gemm<1, 2><<<g2, 256, 0, stream>>>(W, vT, D, N,
                                           nullptr, nullptr, nullptr, nullptr,
                                           part, M, denom, out, row0, D);
  }
}

// Round 4
// 226.853 us; speedup vs baseline: 1.3917x; 1.2467x over previous
//
#include <hip/hip_runtime.h>
#include <hip/hip_bf16.h>

typedef __attribute__((ext_vector_type(8))) short short8;
typedef __attribute__((ext_vector_type(4))) float f32x4;
typedef __attribute__((ext_vector_type(4))) unsigned short u16x4;

__device__ __forceinline__ unsigned short f2bf(float f) {
  union { float f; unsigned u; } v; v.f = f;
  unsigned r = v.u + 0x7fffu + ((v.u >> 16) & 1u);
  return (unsigned short)(r >> 16);
}

// C = A * Bt^T, tile 128x128, BK=32, double-buffered. 512 threads = 8 waves
// arranged 4m x 2n; each wave owns 32 rows x 64 cols (acc[2][4] f32x4).
// LDS: 2 halves x (A[128][32] + B[128][32]) bf16 = 32 KB, shared with the
// W-bounce tile in EPI=0's epilogue.
// Swizzle: LDS slot s=4r+c holds global chunk (r, c^((r>>1)&3)); 8 consecutive
// rows span 8 bank-quads -> 2-way (free). Applied global-side + reader-side.
// EPI=0: epilogue -> W bf16 (LDS bounce, coalesced) + row-sum partials
// EPI=1: epilogue -> out fp32 scaled by 1/(denin+1e-8)
template <int EPI>
__global__ __launch_bounds__(512, 4) void rbf_gemm(
    const unsigned short* __restrict__ A, const unsigned short* __restrict__ Bt,
    int Ncols, int K,
    const float* __restrict__ xsq, const float* __restrict__ psq,
    const float* __restrict__ rtemp, unsigned short* __restrict__ Wout,
    float* __restrict__ part, int Mtot, const float* __restrict__ denin,
    float* __restrict__ outp, int row0, int ldOut) {
  constexpr int HALF = 8192;  // elems per dbuf half (A 4096 + B 4096)
  __shared__ __align__(16) unsigned short smem[16384];

  const int t = threadIdx.x;
  const int lane = t & 63, wid = t >> 6;
  const int wr = wid >> 1, wc = wid & 1;   // 4m x 2n waves
  const int lr = lane & 15, lg = lane >> 4;

  const int nb = Ncols >> 7;
  const int nwg = gridDim.x;
  int swz = blockIdx.x;
  if ((nwg & 7) == 0) {  // bijective XCD swizzle
    int cpx = nwg >> 3;
    swz = (swz & 7) * cpx + (swz >> 3);
  }
  const int bm = swz / nb, bn = swz - bm * nb;

  const unsigned short* Ab = A + (size_t)bm * 128 * K;
  const unsigned short* Bb = Bt + (size_t)bn * 128 * K;

  // --- staging addresses (hoisted; advance by +32 elems per step) ---
  const int sr = t >> 2, sc = t & 3;
  const int scs = sc ^ ((sr >> 1) & 3);     // swizzled source chunk
  const unsigned short* gA = Ab + (size_t)sr * K + scs * 8;
  const unsigned short* gB = Bb + (size_t)sr * K + scs * 8;
  const int dbase = wid << 9;               // wave-uniform LDS base (elems)

  // --- fragment LDS element offsets (reader applies same swizzle) ---
  int offA[2], offB[4];
#pragma unroll
  for (int mi = 0; mi < 2; ++mi) {
    const int ar = wr * 32 + mi * 16 + lr;
    offA[mi] = ar * 32 + ((lg ^ ((ar >> 1) & 3)) << 3);
  }
#pragma unroll
  for (int ni = 0; ni < 4; ++ni) {
    const int br = wc * 64 + ni * 16 + lr;
    offB[ni] = 4096 + br * 32 + ((lg ^ ((br >> 1) & 3)) << 3);
  }

  f32x4 acc[2][4];
#pragma unroll
  for (int i = 0; i < 2; ++i)
#pragma unroll
    for (int j = 0; j < 4; ++j) acc[i][j] = (f32x4){0.f, 0.f, 0.f, 0.f};

#define STAGE(koff, boff)                                                          \
  do {                                                                             \
    __builtin_amdgcn_global_load_lds(                                              \
        (const __attribute__((address_space(1))) void*)(gA + (koff)),              \
        (__attribute__((address_space(3))) void*)(smem + (boff) + dbase), 16, 0, 0); \
    __builtin_amdgcn_global_load_lds(                                              \
        (const __attribute__((address_space(1))) void*)(gB + (koff)),              \
        (__attribute__((address_space(3))) void*)(smem + (boff) + 4096 + dbase), 16, 0, 0); \
  } while (0)

  STAGE(0, 0);
  __syncthreads();
  unsigned boff = 0;
  const int nsteps = K >> 5;
  for (int s = 0; s < nsteps; ++s) {
    if (s + 1 < nsteps) STAGE((s + 1) << 5, boff ^ HALF);  // prefetch next
    const unsigned short* sb = smem + boff;
    short8 af[2], bf[4];
#pragma unroll
    for (int mi = 0; mi < 2; ++mi) af[mi] = *(const short8*)&sb[offA[mi]];
#pragma unroll
    for (int ni = 0; ni < 4; ++ni) bf[ni] = *(const short8*)&sb[offB[ni]];
#pragma unroll
    for (int mi = 0; mi < 2; ++mi)
#pragma unroll
      for (int ni = 0; ni < 4; ++ni)
        acc[mi][ni] = __builtin_amdgcn_mfma_f32_16x16x32_bf16(af[mi], bf[ni],
                                                              acc[mi][ni], 0, 0, 0);
    __syncthreads();  // drains vmcnt: prefetched tile landed; all reads done
    boff ^= HALF;
  }
#undef STAGE

  if (EPI == 0) {
    float xv[2][4];
#pragma unroll
    for (int mi = 0; mi < 2; ++mi)
#pragma unroll
      for (int j = 0; j < 4; ++j)
        xv[mi][j] = xsq[row0 + bm * 128 + wr * 32 + mi * 16 + lg * 4 + j];

    float rs[2][4];
#pragma unroll
    for (int mi = 0; mi < 2; ++mi)
#pragma unroll
      for (int j = 0; j < 4; ++j) rs[mi][j] = 0.f;

#pragma unroll
    for (int ni = 0; ni < 4; ++ni) {
      const int lcol = wc * 64 + ni * 16 + lr;
      const int col = bn * 128 + lcol;
      const float ps = psq[col];
      const float rt = rtemp[col];
      const int h = lcol >> 3;
#pragma unroll
      for (int mi = 0; mi < 2; ++mi) {
#pragma unroll
        for (int j = 0; j < 4; ++j) {
          const int lrow = wr * 32 + mi * 16 + lg * 4 + j;
          float d2 = xv[mi][j] + ps - 2.0f * acc[mi][ni][j];
          float dist = __builtin_amdgcn_sqrtf(fmaxf(d2, 0.0f));
          float wgt = __expf(-dist * rt);
          smem[lrow * 128 + ((h ^ (lrow & 15)) << 3) + (lcol & 7)] = f2bf(wgt);
          rs[mi][j] += wgt;
        }
      }
    }
    __syncthreads();
    // coalesced copy-out: 2048 16B-chunks, 4 rounds of 512 lanes
#pragma unroll
    for (int i = 0; i < 4; ++i) {
      const int id = i * 512 + t;
      const int r = id >> 4, h = id & 15;
      short8 v = *(const short8*)&smem[r * 128 + ((h ^ (r & 15)) << 3)];
      *(short8*)&Wout[(size_t)(bm * 128 + r) * ldOut + bn * 128 + h * 8] = v;
    }
    // row-sum partials: unique writer per (bn,wc,row) -> no atomics
    float* slice = part + (size_t)((bn << 1) | wc) * Mtot;
#pragma unroll
    for (int mi = 0; mi < 2; ++mi)
#pragma unroll
      for (int j = 0; j < 4; ++j) {
        float v = rs[mi][j];
        v += __shfl_xor(v, 1);
        v += __shfl_xor(v, 2);
        v += __shfl_xor(v, 4);
        v += __shfl_xor(v, 8);
        if (lr == 0) {
          const int grow = row0 + bm * 128 + wr * 32 + mi * 16 + lg * 4 + j;
          slice[grow] = v;
        }
      }
  } else {
#pragma unroll
    for (int mi = 0; mi < 2; ++mi) {
#pragma unroll
      for (int j = 0; j < 4; ++j) {
        const int grow = row0 + bm * 128 + wr * 32 + mi * 16 + lg * 4 + j;
        const float rd = 1.0f / (denin[grow] + 1e-8f);
#pragma unroll
        for (int ni = 0; ni < 4; ++ni) {
          const int col = bn * 128 + wc * 64 + ni * 16 + lr;
          outp[(size_t)grow * ldOut + col] = acc[mi][ni][j] * rd;
        }
      }
    }
  }
}

// denom[m] = sum_s part[s][m]
__global__ void reduce_denom(const float* __restrict__ part, float* __restrict__ denom,
                             int Mtot, int row0, int S) {
  const int m = row0 + blockIdx.x * 128 + threadIdx.x;
  float s = 0.f;
  for (int i = 0; i < S; ++i) s += part[(size_t)i * Mtot + m];
  denom[m] = s;
}

// One block per row: cast fp32 row -> bf16, compute sum of squares.
__global__ void prep_rows(const float* __restrict__ in, unsigned short* __restrict__ outb,
                          float* __restrict__ sq, int D) {
  const int row = blockIdx.x;
  const int t = threadIdx.x;
  const float4 v = ((const float4*)(in + (size_t)row * D))[t];
  u16x4 o = {f2bf(v.x), f2bf(v.y), f2bf(v.z), f2bf(v.w)};
  *(u16x4*)(outb + (size_t)row * D + t * 4) = o;
  float s = v.x * v.x + v.y * v.y + v.z * v.z + v.w * v.w;
  for (int off = 32; off; off >>= 1) s += __shfl_xor(s, off);
  __shared__ float ws[16];
  if ((t & 63) == 0) ws[t >> 6] = s;
  __syncthreads();
  if (t == 0) {
    float tot = 0.f;
    const int nw = blockDim.x >> 6;
    for (int i = 0; i < nw; ++i) tot += ws[i];
    sq[row] = tot;
  }
}

__global__ void prep_scale(const float* __restrict__ tmp, const float* __restrict__ sc,
                           float* __restrict__ rtemp, int N) {
  const int i = blockIdx.x * blockDim.x + threadIdx.x;
  if (i < N) rtemp[i] = 1.0f / ((fabsf(tmp[i]) + 0.1f) * sc[i]);
}

// Transpose values [N][D] fp32 -> vT [D][N] bf16
__global__ void prep_vT(const float* __restrict__ vals, unsigned short* __restrict__ vT,
                        int N, int D) {
  __shared__ float tile[32][33];
  const int nt = blockIdx.x, dt = blockIdx.y;
  const int tx = threadIdx.x, ty = threadIdx.y;  // (32, 8)
#pragma unroll
  for (int i = 0; i < 4; ++i) {
    int r = nt * 32 + ty + i * 8;
    tile[ty + i * 8][tx] = vals[(size_t)r * D + dt * 32 + tx];
  }
  __syncthreads();
#pragma unroll
  for (int i = 0; i < 4; ++i) {
    int d = dt * 32 + ty + i * 8;
    vT[(size_t)d * N + nt * 32 + tx] = f2bf(tile[tx][ty + i * 8]);
  }
}

extern "C" void kernel_launch(void* const* d_in, const int* in_sizes, int n_in,
                              void* d_out, int out_size, void* d_ws, size_t ws_size,
                              hipStream_t stream) {
  const float* x = (const float*)d_in[0];
  const float* pos = (const float*)d_in[1];
  const float* vals = (const float*)d_in[2];
  const float* temp = (const float*)d_in[3];
  const float* nsc = (const float*)d_in[4];
  float* out = (float*)d_out;

  const int N = in_sizes[3];          // 4096
  const int D = in_sizes[1] / N;      // 512
  const int M = in_sizes[0] / D;      // 16384
  const int S = 2 * (N / 128);        // partial slices (64)

  char* ws = (char*)d_ws;
  size_t off = 0;
  auto alloc = [&](size_t bytes) {
    void* p = ws + off;
    off = (off + bytes + 255) & ~(size_t)255;
    return p;
  };
  unsigned short* xb = (unsigned short*)alloc((size_t)M * D * 2);
  unsigned short* pb = (unsigned short*)alloc((size_t)N * D * 2);
  unsigned short* vT = (unsigned short*)alloc((size_t)D * N * 2);
  float* xsq = (float*)alloc((size_t)M * 4);
  float* psq = (float*)alloc((size_t)N * 4);
  float* rtemp = (float*)alloc((size_t)N * 4);
  float* denom = (float*)alloc((size_t)M * 4);
  float* part = (float*)alloc((size_t)S * M * 4);

  size_t avail = ws_size > off ? ws_size - off : 0;
  long long mc_ll = (long long)(avail / ((size_t)N * 2));
  int Mc = (int)((mc_ll / 128) * 128);
  if (Mc > M) Mc = M;
  if (Mc < 128) Mc = 128;  // minimal fallback
  unsigned short* W = (unsigned short*)alloc((size_t)Mc * N * 2);

  prep_rows<<<M, D / 4, 0, stream>>>(x, xb, xsq, D);
  prep_rows<<<N, D / 4, 0, stream>>>(pos, pb, psq, D);
  prep_scale<<<(N + 255) / 256, 256, 0, stream>>>(temp, nsc, rtemp, N);
  dim3 tg(N / 32, D / 32);
  prep_vT<<<tg, dim3(32, 8), 0, stream>>>(vals, vT, N, D);

  for (int row0 = 0; row0 < M; row0 += Mc) {
    const int mc = (M - row0) < Mc ? (M - row0) : Mc;
    const int g1 = (mc / 128) * (N / 128);
    rbf_gemm<0><<<g1, 512, 0, stream>>>(xb + (size_t)row0 * D, pb, N, D,
                                        xsq, psq, rtemp, W, part, M,
                                        nullptr, nullptr, row0, N);
    reduce_denom<<<mc / 128, 128, 0, stream>>>(part, denom, M, row0, S);
    const int g2 = (mc / 128) * (D / 128);
    rbf_gemm<1><<<g2, 512, 0, stream>>>(W, vT, D, N,
                                        nullptr, nullptr, nullptr, nullptr,
                                        part, M, denom, out, row0, D);
  }
}